// Round 7
// baseline (1699.791 us; speedup 1.0000x reference)
//
#include <hip/hip_runtime.h>
#include <math.h>

#define BB 8
#define MM 2048
#define NNP 2048
#define THR2 0.25f
#define NITER 10
#define NPART 17
#define TPB 1024
#define NW (TPB / 64)           // 16 waves
#define GD 16                   // grid cells per dim
#define NCELL (GD * GD * GD)    // 4096

// ---------------- Kabsch via Jacobi eigen of H^T H (float, H normalized ~O(1)) ----------------
__device__ void kabsch3f(const float H[3][3], float R[3][3])
{
    float A[3][3];
    for (int i = 0; i < 3; ++i)
        for (int j = 0; j < 3; ++j) {
            float s = 0.0f;
            for (int k = 0; k < 3; ++k) s += H[k][i] * H[k][j];
            A[i][j] = s;
        }
    float V[3][3] = {{1,0,0},{0,1,0},{0,0,1}};
    const float nrm = A[0][0]*A[0][0] + A[1][1]*A[1][1] + A[2][2]*A[2][2] + 1e-30f;
    for (int sweep = 0; sweep < 8; ++sweep) {
        const float off = A[0][1]*A[0][1] + A[0][2]*A[0][2] + A[1][2]*A[1][2];
        if (off < 1e-14f * nrm) break;
        for (int pi = 0; pi < 3; ++pi) {
            const int p = (pi == 2) ? 1 : 0;
            const int q = (pi == 0) ? 1 : 2;
            const float apq = A[p][q];
            if (apq == 0.0f) continue;
            const float theta = (A[q][q] - A[p][p]) / (2.0f * apq);
            const float t = ((theta >= 0.0f) ? 1.0f : -1.0f) / (fabsf(theta) + sqrtf(theta * theta + 1.0f));
            const float c = 1.0f / sqrtf(t * t + 1.0f);
            const float s = t * c;
            const float app = A[p][p], aqq = A[q][q];
            A[p][p] = app - t * apq;
            A[q][q] = aqq + t * apq;
            A[p][q] = 0.0f; A[q][p] = 0.0f;
            const int r = 3 - p - q;
            const float arp = A[r][p], arq = A[r][q];
            A[r][p] = c * arp - s * arq; A[p][r] = A[r][p];
            A[r][q] = s * arp + c * arq; A[q][r] = A[r][q];
            for (int rr = 0; rr < 3; ++rr) {
                const float vrp = V[rr][p], vrq = V[rr][q];
                V[rr][p] = c * vrp - s * vrq;
                V[rr][q] = s * vrp + c * vrq;
            }
        }
    }
    float lam[3] = {A[0][0], A[1][1], A[2][2]};
    int ord[3] = {0, 1, 2};
    for (int i = 0; i < 2; ++i)
        for (int j = i + 1; j < 3; ++j)
            if (lam[ord[j]] > lam[ord[i]]) { const int tmp = ord[i]; ord[i] = ord[j]; ord[j] = tmp; }
    float Vs[3][3], U[3][3];
    for (int k = 0; k < 3; ++k) {
        const int c0 = ord[k];
        const float sk = sqrtf(fmaxf(lam[c0], 0.0f));
        const float inv = (sk > 1e-12f) ? 1.0f / sk : 0.0f;
        for (int i = 0; i < 3; ++i) {
            Vs[i][k] = V[i][c0];
            U[i][k] = (H[i][0] * V[0][c0] + H[i][1] * V[1][c0] + H[i][2] * V[2][c0]) * inv;
        }
    }
    const float detH = H[0][0] * (H[1][1] * H[2][2] - H[1][2] * H[2][1])
                     - H[0][1] * (H[1][0] * H[2][2] - H[1][2] * H[2][0])
                     + H[0][2] * (H[1][0] * H[2][1] - H[1][1] * H[2][0]);
    const float d = (detH < 0.0f) ? -1.0f : 1.0f;
    for (int i = 0; i < 3; ++i)
        for (int j = 0; j < 3; ++j)
            R[i][j] = Vs[i][0] * U[j][0] + Vs[i][1] * U[j][1] + d * Vs[i][2] * U[j][2];
}

// ---------------- one block per batch: LDS uniform-grid NN, zero cross-block sync ----------------
__global__ __launch_bounds__(TPB) void icp_grid(
    const float* __restrict__ pc_src,
    const float* __restrict__ pc_dest,
    const float* __restrict__ init_R,
    const float* __restrict__ init_t,
    float* __restrict__ out)
{
    const int b = blockIdx.x;
    const int tid = threadIdx.x;
    const int wid = tid >> 6;
    const int lane = tid & 63;

    __shared__ float4 dpt[NNP];             // 32 KB dest points
    __shared__ unsigned cnt[NCELL];         // 16 KB: counts -> inclusive ends -> starts
    __shared__ unsigned short sidx[NNP];    // 4 KB sorted point ids
    __shared__ float smom[NW][NPART];
    __shared__ float Sfin[NPART];
    __shared__ float Rt[12];
    __shared__ float sred6[NW][6];
    __shared__ unsigned swsum[NW];
    __shared__ unsigned nvalid_s;
    __shared__ int anyf;
    __shared__ float gp[4];                 // ox, oy, oz, invh

    if (tid == 0) anyf = 0;
    if (tid < 9) Rt[tid] = init_R[b * 9 + tid];
    if (tid < 3) Rt[9 + tid] = init_t[b * 3 + tid];

    // ---- load dest (2 points per thread), validity, min/max ----
    const float dx0 = pc_dest[(b * 3 + 0) * NNP + tid];
    const float dy0 = pc_dest[(b * 3 + 1) * NNP + tid];
    const float dz0 = pc_dest[(b * 3 + 2) * NNP + tid];
    const float dx1 = pc_dest[(b * 3 + 0) * NNP + tid + TPB];
    const float dy1 = pc_dest[(b * 3 + 1) * NNP + tid + TPB];
    const float dz1 = pc_dest[(b * 3 + 2) * NNP + tid + TPB];
    const bool v0 = (dx0 != 0.0f) && (dy0 != 0.0f) && (dz0 != 0.0f);
    const bool v1 = (dx1 != 0.0f) && (dy1 != 0.0f) && (dz1 != 0.0f);
    dpt[tid]       = make_float4(dx0, dy0, dz0, 0.0f);
    dpt[tid + TPB] = make_float4(dx1, dy1, dz1, 0.0f);
    {
        const unsigned long long bal = __ballot(v0 || v1);
        if (lane == 0 && bal) atomicOr(&anyf, 1);
    }
    float mnx = v0 ? dx0 : INFINITY,  mny = v0 ? dy0 : INFINITY,  mnz = v0 ? dz0 : INFINITY;
    float mxx = v0 ? dx0 : -INFINITY, mxy = v0 ? dy0 : -INFINITY, mxz = v0 ? dz0 : -INFINITY;
    if (v1) {
        mnx = fminf(mnx, dx1); mny = fminf(mny, dy1); mnz = fminf(mnz, dz1);
        mxx = fmaxf(mxx, dx1); mxy = fmaxf(mxy, dy1); mxz = fmaxf(mxz, dz1);
    }
    #pragma unroll
    for (int off = 32; off >= 1; off >>= 1) {
        mnx = fminf(mnx, __shfl_xor(mnx, off)); mny = fminf(mny, __shfl_xor(mny, off));
        mnz = fminf(mnz, __shfl_xor(mnz, off)); mxx = fmaxf(mxx, __shfl_xor(mxx, off));
        mxy = fmaxf(mxy, __shfl_xor(mxy, off)); mxz = fmaxf(mxz, __shfl_xor(mxz, off));
    }
    if (lane == 0) {
        sred6[wid][0] = mnx; sred6[wid][1] = mny; sred6[wid][2] = mnz;
        sred6[wid][3] = mxx; sred6[wid][4] = mxy; sred6[wid][5] = mxz;
    }
    #pragma unroll
    for (int i = 0; i < NCELL / TPB; ++i) cnt[tid + i * TPB] = 0u;
    __syncthreads();
    if (tid == 0) {
        float ax = INFINITY, ay = INFINITY, az = INFINITY;
        float bx = -INFINITY, by = -INFINITY, bz = -INFINITY;
        for (int w = 0; w < NW; ++w) {
            ax = fminf(ax, sred6[w][0]); ay = fminf(ay, sred6[w][1]); az = fminf(az, sred6[w][2]);
            bx = fmaxf(bx, sred6[w][3]); by = fmaxf(by, sred6[w][4]); bz = fmaxf(bz, sred6[w][5]);
        }
        float range = fmaxf(fmaxf(bx - ax, by - ay), bz - az);
        if (!(range >= 0.0f)) { ax = ay = az = 0.0f; range = 0.0f; }   // no valid dest
        const float h = fmaxf(0.5f, range * (1.0f / 15.5f));
        gp[0] = ax; gp[1] = ay; gp[2] = az; gp[3] = 1.0f / h;
    }
    __syncthreads();
    const float ox = gp[0], oy = gp[1], oz = gp[2], invh = gp[3];

    // ---- counting sort: count ----
    int c0r = -1, c1r = -1;
    if (v0) {
        const int cx = min(GD - 1, max(0, (int)((dx0 - ox) * invh)));
        const int cy = min(GD - 1, max(0, (int)((dy0 - oy) * invh)));
        const int cz = min(GD - 1, max(0, (int)((dz0 - oz) * invh)));
        c0r = (cz * GD + cy) * GD + cx;
        atomicAdd(&cnt[c0r], 1u);
    }
    if (v1) {
        const int cx = min(GD - 1, max(0, (int)((dx1 - ox) * invh)));
        const int cy = min(GD - 1, max(0, (int)((dy1 - oy) * invh)));
        const int cz = min(GD - 1, max(0, (int)((dz1 - oz) * invh)));
        c1r = (cz * GD + cy) * GD + cx;
        atomicAdd(&cnt[c1r], 1u);
    }
    __syncthreads();

    // ---- block exclusive scan over 4096 cells (4 per thread) -> inclusive ends ----
    const unsigned e0 = cnt[tid * 4 + 0], e1 = cnt[tid * 4 + 1];
    const unsigned e2 = cnt[tid * 4 + 2], e3 = cnt[tid * 4 + 3];
    const unsigned sthr = e0 + e1 + e2 + e3;
    unsigned vsc = sthr;
    #pragma unroll
    for (int off = 1; off < 64; off <<= 1) {
        const unsigned u = __shfl_up(vsc, off);
        if (lane >= off) vsc += u;
    }
    if (lane == 63) swsum[wid] = vsc;
    __syncthreads();
    if (tid == 0) {
        unsigned run = 0;
        for (int w = 0; w < NW; ++w) { const unsigned t = swsum[w]; swsum[w] = run; run += t; }
        nvalid_s = run;
    }
    __syncthreads();
    const unsigned tbase = swsum[wid] + (vsc - sthr);
    cnt[tid * 4 + 0] = tbase + e0;
    cnt[tid * 4 + 1] = tbase + e0 + e1;
    cnt[tid * 4 + 2] = tbase + e0 + e1 + e2;
    cnt[tid * 4 + 3] = tbase + e0 + e1 + e2 + e3;
    __syncthreads();

    // ---- scatter (backward fill); afterwards cnt[c] = start[c] ----
    if (v0) { const unsigned p = atomicSub(&cnt[c0r], 1u) - 1u; sidx[p] = (unsigned short)tid; }
    if (v1) { const unsigned p = atomicSub(&cnt[c1r], 1u) - 1u; sidx[p] = (unsigned short)(tid + TPB); }
    __syncthreads();
    const unsigned nvalid = nvalid_s;
    const float av = anyf ? 1.0f : 0.0f;

    // ---- this thread's 2 source points (reference uses batch-0 source for all batches) ----
    const float sx0 = pc_src[0 * MM + tid], sy0 = pc_src[1 * MM + tid], sz0 = pc_src[2 * MM + tid];
    const float sx1 = pc_src[0 * MM + tid + TPB], sy1 = pc_src[1 * MM + tid + TPB], sz1 = pc_src[2 * MM + tid + TPB];

    for (int it = 0; it <= NITER; ++it) {
        const float R0 = Rt[0], R1 = Rt[1], R2 = Rt[2];
        const float R3 = Rt[3], R4 = Rt[4], R5 = Rt[5];
        const float R6 = Rt[6], R7 = Rt[7], R8 = Rt[8];
        const float T0 = Rt[9], T1 = Rt[10], T2 = Rt[11];

        float acc[NPART];
        #pragma unroll
        for (int k = 0; k < NPART; ++k) acc[k] = 0.0f;

        auto do_m = [&](float sx, float sy, float sz) {
            const float px = fmaf(R0, sx, fmaf(R1, sy, fmaf(R2, sz, T0)));
            const float py = fmaf(R3, sx, fmaf(R4, sy, fmaf(R5, sz, T1)));
            const float pz = fmaf(R6, sx, fmaf(R7, sy, fmaf(R8, sz, T2)));
            const int cx = min(GD - 1, max(0, (int)((px - ox) * invh)));
            const int cy = min(GD - 1, max(0, (int)((py - oy) * invh)));
            const int cz = min(GD - 1, max(0, (int)((pz - oz) * invh)));
            const int x0 = max(cx - 1, 0), x1 = min(cx + 1, GD - 1);
            const int y0 = max(cy - 1, 0), y1 = min(cy + 1, GD - 1);
            const int z0 = max(cz - 1, 0), z1 = min(cz + 1, GD - 1);
            float best = INFINITY;
            int bn = -1;
            for (int z = z0; z <= z1; ++z)
                for (int y = y0; y <= y1; ++y) {
                    const int crow = (z * GD + y) * GD;
                    // x cells are contiguous in the sort: one merged candidate range
                    const unsigned s = cnt[crow + x0];
                    const unsigned e = (crow + x1 + 1 < NCELL) ? cnt[crow + x1 + 1] : nvalid;
                    for (unsigned i = s; i < e; ++i) {
                        const int n = sidx[i];
                        const float4 q = dpt[n];
                        const float ex = px - q.x, ey = py - q.y, ez = pz - q.z;
                        const float d2 = fmaf(ex, ex, fmaf(ey, ey, ez * ez));
                        if (d2 < best || (d2 == best && n < bn)) { best = d2; bn = n; }
                    }
                }
            if (bn >= 0 && best < THR2) {
                const float w = av;
                const float4 q = dpt[bn];
                acc[0] += w;
                acc[1] += w * sx;  acc[2] += w * sy;  acc[3] += w * sz;
                acc[4] += w * q.x; acc[5] += w * q.y; acc[6] += w * q.z;
                acc[7]  += w * sx * q.x; acc[8]  += w * sx * q.y; acc[9]  += w * sx * q.z;
                acc[10] += w * sy * q.x; acc[11] += w * sy * q.y; acc[12] += w * sy * q.z;
                acc[13] += w * sz * q.x; acc[14] += w * sz * q.y; acc[15] += w * sz * q.z;
                acc[16] += w * best;
            }
        };
        do_m(sx0, sy0, sz0);
        do_m(sx1, sy1, sz1);

        // ---- block reduction of 17 moments ----
        #pragma unroll
        for (int k = 0; k < NPART; ++k) {
            float x = acc[k];
            x += __shfl_xor(x, 32); x += __shfl_xor(x, 16); x += __shfl_xor(x, 8);
            x += __shfl_xor(x, 4);  x += __shfl_xor(x, 2);  x += __shfl_xor(x, 1);
            acc[k] = x;
        }
        if (lane == 0) {
            #pragma unroll
            for (int k = 0; k < NPART; ++k) smom[wid][k] = acc[k];
        }
        __syncthreads();
        if (tid < NPART) {
            float ssum = 0.0f;
            #pragma unroll
            for (int w = 0; w < NW; ++w) ssum += smom[w][tid];
            Sfin[tid] = ssum;
        }
        __syncthreads();

        if (it == NITER) break;

        // ---- thread 0: Kabsch update ----
        if (tid == 0) {
            const float wsum = Sfin[0];
            if (wsum >= 0.5f) {
                const float safe = fmaxf(wsum, 1.0f);
                const float inv = 1.0f / safe;
                float mup[3], muq[3];
                for (int i = 0; i < 3; ++i) { mup[i] = Sfin[1 + i] * inv; muq[i] = Sfin[4 + i] * inv; }
                float H[3][3];
                for (int i = 0; i < 3; ++i)
                    for (int j = 0; j < 3; ++j)
                        H[i][j] = (Sfin[7 + i * 3 + j] * inv) - mup[i] * muq[j];
                float R[3][3];
                kabsch3f(H, R);
                for (int i = 0; i < 3; ++i) {
                    for (int j = 0; j < 3; ++j) Rt[i * 3 + j] = R[i][j];
                    Rt[9 + i] = muq[i] - (R[i][0] * mup[0] + R[i][1] * mup[1] + R[i][2] * mup[2]);
                }
            }
        }
        __syncthreads();
    }

    // ---- outputs ----
    if (tid == 0) {
        const float wsum = Sfin[0];
        const float safe = fmaxf(wsum, 1.0f);
        const float rmse = sqrtf(Sfin[16] / safe);
        out[96 + b] = (wsum > 0.0f) ? rmse : __builtin_nanf("");
    }
    if (tid < 9) out[b * 9 + tid] = Rt[tid];
    if (tid < 3) out[72 + b * 3 + tid] = Rt[9 + tid];
}

extern "C" void kernel_launch(void* const* d_in, const int* in_sizes, int n_in,
                              void* d_out, int out_size, void* d_ws, size_t ws_size,
                              hipStream_t stream) {
    const float* pc_src  = (const float*)d_in[0];
    const float* pc_dest = (const float*)d_in[1];
    const float* init_R  = (const float*)d_in[2];
    const float* init_t  = (const float*)d_in[3];
    float* out = (float*)d_out;

    icp_grid<<<BB, TPB, 0, stream>>>(pc_src, pc_dest, init_R, init_t, out);
}

// Round 8
// 497.566 us; speedup vs baseline: 3.4162x; 3.4162x over previous
//
#include <hip/hip_runtime.h>
#include <math.h>

#define BB 8
#define MM 2048
#define NNP 2048
#define THR2 0.25f
#define NITER 10
#define SLOTS (NITER + 1)
#define NPART 17
#define TPB 1024
#define WPB 16                  // waves per block (8 pairs)
#define GRIDB 256               // one block per CU
#define BPB (GRIDB / BB)        // 32 blocks per batch
#define TM 8                    // source points per wave-pair
#define HALF (NNP / 2)          // dest points per wave of a pair
#define STEPS (HALF / 64)       // 16 ds_read_b128 per wave per iteration

// ---- ws layout (element counts) ----
#define ACC_N (SLOTS * BB * 32)     // float accum[SLOTS][BB][32] (17 used)
#define RT_N  (SLOTS * BB * 16)     // float rtpub[SLOTS][BB][16] (12 used)
#define CN_N  (SLOTS * BB)          // uint arrive / flag

__device__ inline float ld_relax_f(const float* p) {
    return __hip_atomic_load(p, __ATOMIC_RELAXED, __HIP_MEMORY_SCOPE_AGENT);
}
__device__ inline unsigned ld_acq_u(const unsigned* p) {
    return __hip_atomic_load(p, __ATOMIC_ACQUIRE, __HIP_MEMORY_SCOPE_AGENT);
}

// ---------------- zero the sync/accumulator region (every call: replay-safe) ----------------
__global__ void zero_kernel(float* __restrict__ accum,
                            unsigned* __restrict__ arrive, unsigned* __restrict__ flag)
{
    const int tid = blockIdx.x * blockDim.x + threadIdx.x;
    if (tid < ACC_N) accum[tid] = 0.0f;
    if (tid < CN_N) { arrive[tid] = 0u; flag[tid] = 0u; }
}

// ---------------- Kabsch via Jacobi eigen of H^T H (float, H normalized ~O(1)) ----------------
__device__ void kabsch3f(const float H[3][3], float R[3][3])
{
    float A[3][3];
    for (int i = 0; i < 3; ++i)
        for (int j = 0; j < 3; ++j) {
            float s = 0.0f;
            for (int k = 0; k < 3; ++k) s += H[k][i] * H[k][j];
            A[i][j] = s;
        }
    float V[3][3] = {{1,0,0},{0,1,0},{0,0,1}};
    const float nrm = A[0][0]*A[0][0] + A[1][1]*A[1][1] + A[2][2]*A[2][2] + 1e-30f;
    for (int sweep = 0; sweep < 8; ++sweep) {
        const float off = A[0][1]*A[0][1] + A[0][2]*A[0][2] + A[1][2]*A[1][2];
        if (off < 1e-14f * nrm) break;
        for (int pi = 0; pi < 3; ++pi) {
            const int p = (pi == 2) ? 1 : 0;
            const int q = (pi == 0) ? 1 : 2;
            const float apq = A[p][q];
            if (apq == 0.0f) continue;
            const float theta = (A[q][q] - A[p][p]) / (2.0f * apq);
            const float t = ((theta >= 0.0f) ? 1.0f : -1.0f) / (fabsf(theta) + sqrtf(theta * theta + 1.0f));
            const float c = 1.0f / sqrtf(t * t + 1.0f);
            const float s = t * c;
            const float app = A[p][p], aqq = A[q][q];
            A[p][p] = app - t * apq;
            A[q][q] = aqq + t * apq;
            A[p][q] = 0.0f; A[q][p] = 0.0f;
            const int r = 3 - p - q;
            const float arp = A[r][p], arq = A[r][q];
            A[r][p] = c * arp - s * arq; A[p][r] = A[r][p];
            A[r][q] = s * arp + c * arq; A[q][r] = A[r][q];
            for (int rr = 0; rr < 3; ++rr) {
                const float vrp = V[rr][p], vrq = V[rr][q];
                V[rr][p] = c * vrp - s * vrq;
                V[rr][q] = s * vrp + c * vrq;
            }
        }
    }
    float lam[3] = {A[0][0], A[1][1], A[2][2]};
    int ord[3] = {0, 1, 2};
    for (int i = 0; i < 2; ++i)
        for (int j = i + 1; j < 3; ++j)
            if (lam[ord[j]] > lam[ord[i]]) { const int tmp = ord[i]; ord[i] = ord[j]; ord[j] = tmp; }
    float Vs[3][3], U[3][3];
    for (int k = 0; k < 3; ++k) {
        const int c0 = ord[k];
        const float sk = sqrtf(fmaxf(lam[c0], 0.0f));
        const float inv = (sk > 1e-12f) ? 1.0f / sk : 0.0f;
        for (int i = 0; i < 3; ++i) {
            Vs[i][k] = V[i][c0];
            U[i][k] = (H[i][0] * V[0][c0] + H[i][1] * V[1][c0] + H[i][2] * V[2][c0]) * inv;
        }
    }
    const float detH = H[0][0] * (H[1][1] * H[2][2] - H[1][2] * H[2][1])
                     - H[0][1] * (H[1][0] * H[2][2] - H[1][2] * H[2][0])
                     + H[0][2] * (H[1][0] * H[2][1] - H[1][1] * H[2][0]);
    const float d = (detH < 0.0f) ? -1.0f : 1.0f;
    for (int i = 0; i < 3; ++i)
        for (int j = 0; j < 3; ++j)
            R[i][j] = Vs[i][0] * U[j][0] + Vs[i][1] * U[j][1] + d * Vs[i][2] * U[j][2];
}

// ---------------- fused ICP: wave-pair scan + leader/publish sync ----------------
__global__ __launch_bounds__(TPB, 4) void icp_fused(
    const float* __restrict__ pc_src,
    const float* __restrict__ pc_dest,
    const float* __restrict__ init_R,
    const float* __restrict__ init_t,
    float* __restrict__ accum,          // [SLOTS][BB][32]
    unsigned* __restrict__ arrive,      // [SLOTS][BB]
    unsigned* __restrict__ flag,        // [SLOTS][BB]
    float* __restrict__ rtpub,          // [SLOTS][BB][16]
    float* __restrict__ out)
{
    const int blk = blockIdx.x;
    const int b = blk & 7;              // batch -> XCD-local under round-robin dispatch
    const int cblk = blk >> 3;          // 0..31 within batch
    const int tid = threadIdx.x;
    const int wid = tid >> 6;
    const int lane = tid & 63;
    const int pairid = wid >> 1;        // 0..7
    const int half = wid & 1;           // 0 = dest[0,1024), 1 = dest[1024,2048)

    __shared__ float4 ds[NNP];          // 32 KB dest: (x,y,z, valid? |d|^2 : INF)
    __shared__ float sminV[WPB][TM];
    __shared__ int   sminI[WPB][TM];
    __shared__ float smom[WPB / 2][NPART];
    __shared__ float Sfin[NPART];
    __shared__ float Rt[12];
    __shared__ int anyf;

    if (tid == 0) anyf = 0;
    if (tid < 9) Rt[tid] = init_R[b * 9 + tid];
    if (tid < 3) Rt[9 + tid] = init_t[b * 3 + tid];
    __syncthreads();

    // stage dest once; fold validity into .w
    for (int n = tid; n < NNP; n += TPB) {
        const float dx = pc_dest[(b * 3 + 0) * NNP + n];
        const float dy = pc_dest[(b * 3 + 1) * NNP + n];
        const float dz = pc_dest[(b * 3 + 2) * NNP + n];
        const bool valid = (dx != 0.0f) && (dy != 0.0f) && (dz != 0.0f);
        const float dd = dx * dx + dy * dy + dz * dz;
        ds[n] = make_float4(dx, dy, dz, valid ? dd : INFINITY);
        const unsigned long long bal = __ballot(valid);
        if (lane == 0 && bal) atomicOr(&anyf, 1);
    }

    // this pair's 8 source points (wave-uniform; reference uses batch-0 source)
    const int m0 = cblk * (WPB / 2 * TM) + pairid * TM;
    float sx[TM], sy[TM], sz[TM];
    #pragma unroll
    for (int t = 0; t < TM; ++t) {
        sx[t] = pc_src[0 * MM + m0 + t];
        sy[t] = pc_src[1 * MM + m0 + t];
        sz[t] = pc_src[2 * MM + m0 + t];
    }
    __syncthreads();
    const float av = anyf ? 1.0f : 0.0f;
    const int base = half * HALF;

    for (int it = 0; it <= NITER; ++it) {
        // ---- transform (argmin key drops per-m constant pp; recovered exactly later) ----
        float nx[TM], ny[TM], nz[TM];
        #pragma unroll
        for (int t = 0; t < TM; ++t) {
            const float px = fmaf(Rt[0], sx[t], fmaf(Rt[1], sy[t], fmaf(Rt[2], sz[t], Rt[9])));
            const float py = fmaf(Rt[3], sx[t], fmaf(Rt[4], sy[t], fmaf(Rt[5], sz[t], Rt[10])));
            const float pz = fmaf(Rt[6], sx[t], fmaf(Rt[7], sy[t], fmaf(Rt[8], sz[t], Rt[11])));
            nx[t] = -2.0f * px; ny[t] = -2.0f * py; nz[t] = -2.0f * pz;
        }

        // ---- scan my half: 1 ds_read_b128 feeds 8 m-chains ----
        float best[TM]; int bidx[TM];
        #pragma unroll
        for (int t = 0; t < TM; ++t) { best[t] = INFINITY; bidx[t] = base + lane; }

        int j = base + lane;
        #pragma unroll 4
        for (int s = 0; s < STEPS; ++s, j += 64) {
            const float4 d = ds[j];
            #pragma unroll
            for (int t = 0; t < TM; ++t) {
                const float e = fmaf(nx[t], d.x, fmaf(ny[t], d.y, fmaf(nz[t], d.z, d.w)));
                if (e < best[t]) { best[t] = e; bidx[t] = j; }
            }
        }

        // ---- per-m cross-lane lex argmin (first-index tie-break) ----
        #pragma unroll
        for (int t = 0; t < TM; ++t) {
            float bv = best[t]; int bn = bidx[t];
            #pragma unroll
            for (int off = 32; off >= 1; off >>= 1) {
                const float ov = __shfl_xor(bv, off);
                const int on = __shfl_xor(bn, off);
                if (ov < bv || (ov == bv && on < bn)) { bv = ov; bn = on; }
            }
            best[t] = bv; bidx[t] = bn;
        }
        if (lane == 0) {
            #pragma unroll
            for (int t = 0; t < TM; ++t) { sminV[wid][t] = best[t]; sminI[wid][t] = bidx[t]; }
        }
        __syncthreads();

        // ---- even wave merges pair halves (tie -> even = lower index), moments ----
        if (!half) {
            float acc[NPART];
            #pragma unroll
            for (int k = 0; k < NPART; ++k) acc[k] = 0.0f;
            #pragma unroll
            for (int t = 0; t < TM; ++t) {
                float bv = best[t]; int bn = bidx[t];
                const float vO = sminV[wid + 1][t];
                const int iO = sminI[wid + 1][t];
                if (vO < bv) { bv = vO; bn = iO; }
                const float4 q = ds[bn];     // wave-uniform broadcast
                const float px = -0.5f * nx[t], py = -0.5f * ny[t], pz = -0.5f * nz[t];
                const float ex = px - q.x, ey = py - q.y, ez = pz - q.z;
                const float d2m = ex * ex + ey * ey + ez * ez;
                const float w = (d2m < THR2) ? av : 0.0f;
                acc[0] += w;
                acc[1] += w * sx[t];  acc[2] += w * sy[t];  acc[3] += w * sz[t];
                acc[4] += w * q.x;    acc[5] += w * q.y;    acc[6] += w * q.z;
                acc[7]  += w * sx[t] * q.x; acc[8]  += w * sx[t] * q.y; acc[9]  += w * sx[t] * q.z;
                acc[10] += w * sy[t] * q.x; acc[11] += w * sy[t] * q.y; acc[12] += w * sy[t] * q.z;
                acc[13] += w * sz[t] * q.x; acc[14] += w * sz[t] * q.y; acc[15] += w * sz[t] * q.z;
                acc[16] += w * d2m;
            }
            if (lane == 0) {
                #pragma unroll
                for (int k = 0; k < NPART; ++k) smom[pairid][k] = acc[k];
            }
        }
        __syncthreads();

        // ---- block moments -> device accumulator (release RMW; no fence) ----
        if (tid < NPART) {
            float s = 0.0f;
            #pragma unroll
            for (int p = 0; p < WPB / 2; ++p) s += smom[p][tid];
            __hip_atomic_fetch_add(&accum[(it * BB + b) * 32 + tid], s,
                                   __ATOMIC_RELEASE, __HIP_MEMORY_SCOPE_AGENT);
        }
        __syncthreads();
        if (tid == 0)
            __hip_atomic_fetch_add(&arrive[it * BB + b], 1u,
                                   __ATOMIC_RELEASE, __HIP_MEMORY_SCOPE_AGENT);

        if (it == NITER) break;

        if (cblk == 0) {
            // ---- leader: wait 32 arrivals, read sums, Kabsch, publish ----
            if (tid == 0) {
                while (ld_acq_u(&arrive[it * BB + b]) < (unsigned)BPB)
                    __builtin_amdgcn_s_sleep(1);
                float S[NPART];
                #pragma unroll
                for (int k = 0; k < NPART; ++k) S[k] = ld_relax_f(&accum[(it * BB + b) * 32 + k]);

                float newRt[12];
                #pragma unroll
                for (int k = 0; k < 12; ++k) newRt[k] = Rt[k];
                const float wsum = S[0];
                if (wsum >= 0.5f) {
                    const float safe = fmaxf(wsum, 1.0f);
                    const float inv = 1.0f / safe;
                    float mup[3], muq[3];
                    for (int i = 0; i < 3; ++i) { mup[i] = S[1 + i] * inv; muq[i] = S[4 + i] * inv; }
                    float H[3][3];
                    for (int i = 0; i < 3; ++i)
                        for (int jj = 0; jj < 3; ++jj)
                            H[i][jj] = (S[7 + i * 3 + jj] * inv) - mup[i] * muq[jj];
                    float R[3][3];
                    kabsch3f(H, R);
                    for (int i = 0; i < 3; ++i) {
                        for (int jj = 0; jj < 3; ++jj) newRt[i * 3 + jj] = R[i][jj];
                        newRt[9 + i] = muq[i] - (R[i][0] * mup[0] + R[i][1] * mup[1] + R[i][2] * mup[2]);
                    }
                }
                #pragma unroll
                for (int k = 0; k < 12; ++k) {
                    __hip_atomic_store(&rtpub[(it * BB + b) * 16 + k], newRt[k],
                                       __ATOMIC_RELAXED, __HIP_MEMORY_SCOPE_AGENT);
                    Rt[k] = newRt[k];
                }
                __hip_atomic_store(&flag[it * BB + b], 1u,
                                   __ATOMIC_RELEASE, __HIP_MEMORY_SCOPE_AGENT);
            }
            __syncthreads();
        } else {
            // ---- followers: wait for published R/t ----
            if (tid == 0) {
                while (ld_acq_u(&flag[it * BB + b]) == 0u)
                    __builtin_amdgcn_s_sleep(1);
                #pragma unroll
                for (int k = 0; k < 12; ++k)
                    Rt[k] = ld_relax_f(&rtpub[(it * BB + b) * 16 + k]);
            }
            __syncthreads();
        }
    }

    // ---- outputs: batch leader only ----
    if (cblk == 0) {
        if (tid == 0) {
            while (ld_acq_u(&arrive[NITER * BB + b]) < (unsigned)BPB)
                __builtin_amdgcn_s_sleep(1);
            const float wsum = ld_relax_f(&accum[(NITER * BB + b) * 32 + 0]);
            const float wd2  = ld_relax_f(&accum[(NITER * BB + b) * 32 + 16]);
            const float safe = fmaxf(wsum, 1.0f);
            const float rmse = sqrtf(wd2 / safe);
            out[96 + b] = (wsum > 0.0f) ? rmse : __builtin_nanf("");
        }
        if (tid < 9) out[b * 9 + tid] = Rt[tid];
        if (tid < 3) out[72 + b * 3 + tid] = Rt[9 + tid];
    }
}

extern "C" void kernel_launch(void* const* d_in, const int* in_sizes, int n_in,
                              void* d_out, int out_size, void* d_ws, size_t ws_size,
                              hipStream_t stream) {
    const float* pc_src  = (const float*)d_in[0];
    const float* pc_dest = (const float*)d_in[1];
    const float* init_R  = (const float*)d_in[2];
    const float* init_t  = (const float*)d_in[3];
    float* out = (float*)d_out;

    float* accum     = (float*)d_ws;                 // ACC_N
    float* rtpub     = accum + ACC_N;                // RT_N
    unsigned* arrive = (unsigned*)(rtpub + RT_N);    // CN_N
    unsigned* flagp  = arrive + CN_N;                // CN_N

    zero_kernel<<<(ACC_N + 1023) / 1024, 1024, 0, stream>>>(accum, arrive, flagp);

    void* args[] = {(void*)&pc_src, (void*)&pc_dest, (void*)&init_R, (void*)&init_t,
                    (void*)&accum, (void*)&arrive, (void*)&flagp, (void*)&rtpub, (void*)&out};
    hipLaunchCooperativeKernel((const void*)icp_fused, dim3(GRIDB), dim3(TPB), args, 0, stream);
}

// Round 9
// 231.988 us; speedup vs baseline: 7.3271x; 2.1448x over previous
//
#include <hip/hip_runtime.h>
#include <math.h>

#define BB 8
#define MM 2048
#define NNP 2048
#define THR2 0.25f
#define NITER 10
#define NPART 17
#define TPB 1024
#define WPB 16                  // waves per block (8 pairs)
#define BPB 32                  // blocks per batch
#define GRIDB (BB * BPB)        // 256
#define TM 8                    // source points per wave-pair
#define HALF (NNP / 2)
#define STEPS (HALF / 64)       // 16 ds_read_b128 per wave per iteration
// partials: [NITER+1][BB][BPB][32] floats (17 used per row)

// ---------------- pack: dest -> float4(x,y,z, valid? |d|^2 : INF), any_valid ----------------
__global__ void pack_kernel(const float* __restrict__ pc_dest,
                            float4* __restrict__ destp,
                            float* __restrict__ anyvalid)
{
    const int b = blockIdx.x;
    const int tid = threadIdx.x;
    __shared__ int anyf;
    if (tid == 0) anyf = 0;
    __syncthreads();
    int local = 0;
    for (int n = tid; n < NNP; n += blockDim.x) {
        const float dx = pc_dest[(b * 3 + 0) * NNP + n];
        const float dy = pc_dest[(b * 3 + 1) * NNP + n];
        const float dz = pc_dest[(b * 3 + 2) * NNP + n];
        const int valid = (dx != 0.0f) && (dy != 0.0f) && (dz != 0.0f);
        const float dd = dx * dx + dy * dy + dz * dz;
        destp[b * NNP + n] = make_float4(dx, dy, dz, valid ? dd : INFINITY);
        local |= valid;
    }
    if (local) atomicOr(&anyf, 1);
    __syncthreads();
    if (tid == 0) anyvalid[b] = (anyf != 0) ? 1.0f : 0.0f;
}

// ---------------- Kabsch via Jacobi eigen of H^T H (float, H normalized ~O(1)) ----------------
__device__ void kabsch3f(const float H[3][3], float R[3][3])
{
    float A[3][3];
    for (int i = 0; i < 3; ++i)
        for (int j = 0; j < 3; ++j) {
            float s = 0.0f;
            for (int k = 0; k < 3; ++k) s += H[k][i] * H[k][j];
            A[i][j] = s;
        }
    float V[3][3] = {{1,0,0},{0,1,0},{0,0,1}};
    const float nrm = A[0][0]*A[0][0] + A[1][1]*A[1][1] + A[2][2]*A[2][2] + 1e-30f;
    for (int sweep = 0; sweep < 8; ++sweep) {
        const float off = A[0][1]*A[0][1] + A[0][2]*A[0][2] + A[1][2]*A[1][2];
        if (off < 1e-14f * nrm) break;
        for (int pi = 0; pi < 3; ++pi) {
            const int p = (pi == 2) ? 1 : 0;
            const int q = (pi == 0) ? 1 : 2;
            const float apq = A[p][q];
            if (apq == 0.0f) continue;
            const float theta = (A[q][q] - A[p][p]) / (2.0f * apq);
            const float t = ((theta >= 0.0f) ? 1.0f : -1.0f) / (fabsf(theta) + sqrtf(theta * theta + 1.0f));
            const float c = 1.0f / sqrtf(t * t + 1.0f);
            const float s = t * c;
            const float app = A[p][p], aqq = A[q][q];
            A[p][p] = app - t * apq;
            A[q][q] = aqq + t * apq;
            A[p][q] = 0.0f; A[q][p] = 0.0f;
            const int r = 3 - p - q;
            const float arp = A[r][p], arq = A[r][q];
            A[r][p] = c * arp - s * arq; A[p][r] = A[r][p];
            A[r][q] = s * arp + c * arq; A[q][r] = A[r][q];
            for (int rr = 0; rr < 3; ++rr) {
                const float vrp = V[rr][p], vrq = V[rr][q];
                V[rr][p] = c * vrp - s * vrq;
                V[rr][q] = s * vrp + c * vrq;
            }
        }
    }
    float lam[3] = {A[0][0], A[1][1], A[2][2]};
    int ord[3] = {0, 1, 2};
    for (int i = 0; i < 2; ++i)
        for (int j = i + 1; j < 3; ++j)
            if (lam[ord[j]] > lam[ord[i]]) { const int tmp = ord[i]; ord[i] = ord[j]; ord[j] = tmp; }
    float Vs[3][3], U[3][3];
    for (int k = 0; k < 3; ++k) {
        const int c0 = ord[k];
        const float sk = sqrtf(fmaxf(lam[c0], 0.0f));
        const float inv = (sk > 1e-12f) ? 1.0f / sk : 0.0f;
        for (int i = 0; i < 3; ++i) {
            Vs[i][k] = V[i][c0];
            U[i][k] = (H[i][0] * V[0][c0] + H[i][1] * V[1][c0] + H[i][2] * V[2][c0]) * inv;
        }
    }
    const float detH = H[0][0] * (H[1][1] * H[2][2] - H[1][2] * H[2][1])
                     - H[0][1] * (H[1][0] * H[2][2] - H[1][2] * H[2][0])
                     + H[0][2] * (H[1][0] * H[2][1] - H[1][1] * H[2][0]);
    const float d = (detH < 0.0f) ? -1.0f : 1.0f;
    for (int i = 0; i < 3; ++i)
        for (int j = 0; j < 3; ++j)
            R[i][j] = Vs[i][0] * U[j][0] + Vs[i][1] * U[j][1] + d * Vs[i][2] * U[j][2];
}

// ---------------- corr: redundant Kabsch from prev partials + wave-pair scan ----------------
__global__ __launch_bounds__(TPB, 4) void corr_kernel(
    const int it,
    const float* __restrict__ pc_src,
    const float4* __restrict__ destp,
    const float* __restrict__ anyvalid,
    const float* __restrict__ init_R,
    const float* __restrict__ init_t,
    float* __restrict__ partials,       // [NITER+1][BB][BPB][32]
    float* __restrict__ out)
{
    const int blk = blockIdx.x;
    const int b = blk / BPB;
    const int cblk = blk % BPB;
    const int tid = threadIdx.x;
    const int wid = tid >> 6;
    const int lane = tid & 63;
    const int pairid = wid >> 1;        // 0..7
    const int half = wid & 1;

    __shared__ float4 ds[NNP];          // 32 KB dest: (x,y,z, valid? |d|^2 : INF)
    __shared__ float sred[BPB * NPART]; // prev-iteration partial rows
    __shared__ float sminV[WPB][TM];
    __shared__ int   sminI[WPB][TM];
    __shared__ float smom[WPB / 2][NPART];
    __shared__ float Sfin[NPART];
    __shared__ float Rt[12];

    // ---- stage packed dest (2 float4 per thread, coalesced) ----
    const float4* db = destp + b * NNP;
    ds[tid]       = db[tid];
    ds[tid + TPB] = db[tid + TPB];

    // ---- load prev partials (kernel boundary made them visible) ----
    if (it > 0) {
        if (tid < BPB * NPART) {
            const int row = tid / NPART, k = tid % NPART;
            sred[tid] = partials[(size_t)(((it - 1) * BB + b) * BPB + row) * 32 + k];
        }
    } else {
        if (tid < 9) Rt[tid] = init_R[b * 9 + tid];
        if (tid < 3) Rt[9 + tid] = init_t[b * 3 + tid];
    }
    __syncthreads();

    if (it > 0) {
        if (tid < NPART) {
            float s = 0.0f;
            #pragma unroll
            for (int c = 0; c < BPB; ++c) s += sred[c * NPART + tid];
            Sfin[tid] = s;
        }
        __syncthreads();
        // ---- redundant per-block Kabsch (identical arithmetic -> deterministic) ----
        if (tid == 0) {
            const float wsum = Sfin[0];
            if (wsum >= 0.5f) {
                const float safe = fmaxf(wsum, 1.0f);
                const float inv = 1.0f / safe;
                float mup[3], muq[3];
                for (int i = 0; i < 3; ++i) { mup[i] = Sfin[1 + i] * inv; muq[i] = Sfin[4 + i] * inv; }
                float H[3][3];
                for (int i = 0; i < 3; ++i)
                    for (int j = 0; j < 3; ++j)
                        H[i][j] = (Sfin[7 + i * 3 + j] * inv) - mup[i] * muq[j];
                float R[3][3];
                kabsch3f(H, R);
                for (int i = 0; i < 3; ++i) {
                    for (int j = 0; j < 3; ++j) Rt[i * 3 + j] = R[i][j];
                    Rt[9 + i] = muq[i] - (R[i][0] * mup[0] + R[i][1] * mup[1] + R[i][2] * mup[2]);
                }
            } else {
                // keep previous R/t: reload from where the previous iteration's
                // consumer would have had it. R/t evolves deterministically from
                // init through identical per-block updates, so recompute path:
                // wsum==0 can only happen if no inliers; reference keeps old R,t.
                // Old R/t for it>0 is not stored globally; reconstruct: it equals
                // the R/t this block used last launch — but blocks are stateless.
                // Fallback: use init (only reachable when dest has no valid points,
                // in which case av==0 for ALL iterations and R/t stays init forever).
                for (int k = 0; k < 9; ++k) Rt[k] = init_R[b * 9 + k];
                for (int k = 0; k < 3; ++k) Rt[9 + k] = init_t[b * 3 + k];
            }
        }
        __syncthreads();
    }

    // ---- final-iteration R/t output ----
    if (it == NITER && cblk == 0) {
        if (tid < 9) out[b * 9 + tid] = Rt[tid];
        if (tid < 3) out[72 + b * 3 + tid] = Rt[9 + tid];
    }

    // ---- this pair's 8 source points (batch-0 source per reference) ----
    const int m0 = cblk * (WPB / 2 * TM) + pairid * TM;
    float sx[TM], sy[TM], sz[TM];
    #pragma unroll
    for (int t = 0; t < TM; ++t) {
        sx[t] = pc_src[0 * MM + m0 + t];
        sy[t] = pc_src[1 * MM + m0 + t];
        sz[t] = pc_src[2 * MM + m0 + t];
    }
    const float av = anyvalid[b];
    const int base = half * HALF;

    // ---- transform (argmin key drops per-m constant |p|^2) ----
    float nx[TM], ny[TM], nz[TM];
    #pragma unroll
    for (int t = 0; t < TM; ++t) {
        const float px = fmaf(Rt[0], sx[t], fmaf(Rt[1], sy[t], fmaf(Rt[2], sz[t], Rt[9])));
        const float py = fmaf(Rt[3], sx[t], fmaf(Rt[4], sy[t], fmaf(Rt[5], sz[t], Rt[10])));
        const float pz = fmaf(Rt[6], sx[t], fmaf(Rt[7], sy[t], fmaf(Rt[8], sz[t], Rt[11])));
        nx[t] = -2.0f * px; ny[t] = -2.0f * py; nz[t] = -2.0f * pz;
    }

    // ---- scan my half: 1 ds_read_b128 feeds 8 m-chains ----
    float best[TM]; int bidx[TM];
    #pragma unroll
    for (int t = 0; t < TM; ++t) { best[t] = INFINITY; bidx[t] = base + lane; }

    int j = base + lane;
    #pragma unroll 4
    for (int s = 0; s < STEPS; ++s, j += 64) {
        const float4 d = ds[j];
        #pragma unroll
        for (int t = 0; t < TM; ++t) {
            const float e = fmaf(nx[t], d.x, fmaf(ny[t], d.y, fmaf(nz[t], d.z, d.w)));
            if (e < best[t]) { best[t] = e; bidx[t] = j; }
        }
    }

    // ---- per-m cross-lane lex argmin (first-index tie-break) ----
    #pragma unroll
    for (int t = 0; t < TM; ++t) {
        float bv = best[t]; int bn = bidx[t];
        #pragma unroll
        for (int off = 32; off >= 1; off >>= 1) {
            const float ov = __shfl_xor(bv, off);
            const int on = __shfl_xor(bn, off);
            if (ov < bv || (ov == bv && on < bn)) { bv = ov; bn = on; }
        }
        best[t] = bv; bidx[t] = bn;
    }
    if (lane == 0) {
        #pragma unroll
        for (int t = 0; t < TM; ++t) { sminV[wid][t] = best[t]; sminI[wid][t] = bidx[t]; }
    }
    __syncthreads();

    // ---- even wave merges pair halves (tie -> even = lower index), moments ----
    if (!half) {
        float acc[NPART];
        #pragma unroll
        for (int k = 0; k < NPART; ++k) acc[k] = 0.0f;
        #pragma unroll
        for (int t = 0; t < TM; ++t) {
            float bv = best[t]; int bn = bidx[t];
            const float vO = sminV[wid + 1][t];
            const int iO = sminI[wid + 1][t];
            if (vO < bv) { bv = vO; bn = iO; }
            const float4 q = ds[bn];     // wave-uniform broadcast
            const float px = -0.5f * nx[t], py = -0.5f * ny[t], pz = -0.5f * nz[t];
            const float ex = px - q.x, ey = py - q.y, ez = pz - q.z;
            const float d2m = ex * ex + ey * ey + ez * ez;
            const float w = (d2m < THR2) ? av : 0.0f;
            acc[0] += w;
            acc[1] += w * sx[t];  acc[2] += w * sy[t];  acc[3] += w * sz[t];
            acc[4] += w * q.x;    acc[5] += w * q.y;    acc[6] += w * q.z;
            acc[7]  += w * sx[t] * q.x; acc[8]  += w * sx[t] * q.y; acc[9]  += w * sx[t] * q.z;
            acc[10] += w * sy[t] * q.x; acc[11] += w * sy[t] * q.y; acc[12] += w * sy[t] * q.z;
            acc[13] += w * sz[t] * q.x; acc[14] += w * sz[t] * q.y; acc[15] += w * sz[t] * q.z;
            acc[16] += w * d2m;
        }
        if (lane == 0) {
            #pragma unroll
            for (int k = 0; k < NPART; ++k) smom[pairid][k] = acc[k];
        }
    }
    __syncthreads();

    // ---- block moments -> this block's partial row ----
    if (tid < NPART) {
        float s = 0.0f;
        #pragma unroll
        for (int p = 0; p < WPB / 2; ++p) s += smom[p][tid];
        partials[(size_t)((it * BB + b) * BPB + cblk) * 32 + tid] = s;
    }
}

// ---------------- finalize: rmse from last partials ----------------
__global__ __launch_bounds__(64) void finalize_kernel(const float* __restrict__ partials,
                                                      float* __restrict__ out)
{
    const int b = blockIdx.x;
    const int lane = threadIdx.x;
    float w = 0.0f, wd = 0.0f;
    if (lane < BPB) {
        const float* row = partials + (size_t)((NITER * BB + b) * BPB + lane) * 32;
        w = row[0];
        wd = row[16];
    }
    #pragma unroll
    for (int off = 16; off >= 1; off >>= 1) {
        w += __shfl_xor(w, off);
        wd += __shfl_xor(wd, off);
    }
    if (lane == 0) {
        const float safe = fmaxf(w, 1.0f);
        const float rmse = sqrtf(wd / safe);
        out[96 + b] = (w > 0.0f) ? rmse : __builtin_nanf("");
    }
}

extern "C" void kernel_launch(void* const* d_in, const int* in_sizes, int n_in,
                              void* d_out, int out_size, void* d_ws, size_t ws_size,
                              hipStream_t stream) {
    const float* pc_src  = (const float*)d_in[0];
    const float* pc_dest = (const float*)d_in[1];
    const float* init_R  = (const float*)d_in[2];
    const float* init_t  = (const float*)d_in[3];
    float* out = (float*)d_out;
    float* ws = (float*)d_ws;

    // ws layout (floats)
    float4* destp   = (float4*)ws;                     // BB*NNP float4
    float* anyvalid = ws + BB * NNP * 4;               // BB
    float* partials = anyvalid + BB;                   // (NITER+1)*BB*BPB*32

    pack_kernel<<<BB, 256, 0, stream>>>(pc_dest, destp, anyvalid);

    for (int it = 0; it <= NITER; ++it) {
        corr_kernel<<<GRIDB, TPB, 0, stream>>>(it, pc_src, destp, anyvalid,
                                               init_R, init_t, partials, out);
    }
    finalize_kernel<<<BB, 64, 0, stream>>>(partials, out);
}

// Round 10
// 206.393 us; speedup vs baseline: 8.2357x; 1.1240x over previous
//
#include <hip/hip_runtime.h>
#include <math.h>

#define BB 8
#define MM 2048
#define NNP 2048
#define THR2 0.25f
#define NITER 10
#define NPART 17
#define TPB 1024
#define WPB 16                  // waves per block (8 pairs)
#define BPB 32                  // blocks per batch
#define GRIDB (BB * BPB)        // 256
#define TM 8                    // source points per wave-pair
#define HALF (NNP / 2)
#define STEPS (HALF / 64)       // 16 ds_read_b128 per wave per iteration
// partials: [NITER+1][BB][BPB][32] floats (17 used per row; rows contiguous per (it,b))
// rtstore:  [BB][16] floats (12 used) — R/t after each launch, for the wsum==0 keep-old path

// ---------------- Jacobi fallback (only for degenerate H: det <= ~0) ----------------
__device__ void kabsch3f(const float H[3][3], float R[3][3])
{
    float A[3][3];
    for (int i = 0; i < 3; ++i)
        for (int j = 0; j < 3; ++j) {
            float s = 0.0f;
            for (int k = 0; k < 3; ++k) s += H[k][i] * H[k][j];
            A[i][j] = s;
        }
    float V[3][3] = {{1,0,0},{0,1,0},{0,0,1}};
    const float nrm = A[0][0]*A[0][0] + A[1][1]*A[1][1] + A[2][2]*A[2][2] + 1e-30f;
    for (int sweep = 0; sweep < 8; ++sweep) {
        const float off = A[0][1]*A[0][1] + A[0][2]*A[0][2] + A[1][2]*A[1][2];
        if (off < 1e-14f * nrm) break;
        for (int pi = 0; pi < 3; ++pi) {
            const int p = (pi == 2) ? 1 : 0;
            const int q = (pi == 0) ? 1 : 2;
            const float apq = A[p][q];
            if (apq == 0.0f) continue;
            const float theta = (A[q][q] - A[p][p]) / (2.0f * apq);
            const float t = ((theta >= 0.0f) ? 1.0f : -1.0f) / (fabsf(theta) + sqrtf(theta * theta + 1.0f));
            const float c = 1.0f / sqrtf(t * t + 1.0f);
            const float s = t * c;
            const float app = A[p][p], aqq = A[q][q];
            A[p][p] = app - t * apq;
            A[q][q] = aqq + t * apq;
            A[p][q] = 0.0f; A[q][p] = 0.0f;
            const int r = 3 - p - q;
            const float arp = A[r][p], arq = A[r][q];
            A[r][p] = c * arp - s * arq; A[p][r] = A[r][p];
            A[r][q] = s * arp + c * arq; A[q][r] = A[r][q];
            for (int rr = 0; rr < 3; ++rr) {
                const float vrp = V[rr][p], vrq = V[rr][q];
                V[rr][p] = c * vrp - s * vrq;
                V[rr][q] = s * vrp + c * vrq;
            }
        }
    }
    float lam[3] = {A[0][0], A[1][1], A[2][2]};
    int ord[3] = {0, 1, 2};
    for (int i = 0; i < 2; ++i)
        for (int j = i + 1; j < 3; ++j)
            if (lam[ord[j]] > lam[ord[i]]) { const int tmp = ord[i]; ord[i] = ord[j]; ord[j] = tmp; }
    float Vs[3][3], U[3][3];
    for (int k = 0; k < 3; ++k) {
        const int c0 = ord[k];
        const float sk = sqrtf(fmaxf(lam[c0], 0.0f));
        const float inv = (sk > 1e-12f) ? 1.0f / sk : 0.0f;
        for (int i = 0; i < 3; ++i) {
            Vs[i][k] = V[i][c0];
            U[i][k] = (H[i][0] * V[0][c0] + H[i][1] * V[1][c0] + H[i][2] * V[2][c0]) * inv;
        }
    }
    const float detH = H[0][0] * (H[1][1] * H[2][2] - H[1][2] * H[2][1])
                     - H[0][1] * (H[1][0] * H[2][2] - H[1][2] * H[2][0])
                     + H[0][2] * (H[1][0] * H[2][1] - H[1][1] * H[2][0]);
    const float d = (detH < 0.0f) ? -1.0f : 1.0f;
    for (int i = 0; i < 3; ++i)
        for (int j = 0; j < 3; ++j)
            R[i][j] = Vs[i][0] * U[j][0] + Vs[i][1] * U[j][1] + d * Vs[i][2] * U[j][2];
}

// ---------------- corr: redundant Kabsch (Newton polar) + wave-pair scan ----------------
__global__ __launch_bounds__(TPB, 4) void corr_kernel(
    const int it,
    const float* __restrict__ pc_src,
    const float* __restrict__ pc_dest,
    const float* __restrict__ init_R,
    const float* __restrict__ init_t,
    float* __restrict__ rtstore,        // [BB][16]
    float* __restrict__ partials,       // [NITER+1][BB][BPB][32]
    float* __restrict__ out)
{
    const int blk = blockIdx.x;
    const int b = blk / BPB;
    const int cblk = blk % BPB;
    const int tid = threadIdx.x;
    const int wid = tid >> 6;
    const int lane = tid & 63;
    const int pairid = wid >> 1;        // 0..7
    const int half = wid & 1;

    __shared__ float4 ds[NNP];          // 32 KB dest: (x,y,z, valid? |d|^2 : INF)
    __shared__ float sred[BPB * 32];    // prev-iteration partial rows (4 KB)
    __shared__ float sminV[WPB][TM];
    __shared__ int   sminI[WPB][TM];
    __shared__ float smom[WPB / 2][NPART];
    __shared__ float Sfin[NPART];
    __shared__ float Rt[12];

    // ---- stage raw dest -> packed LDS (3 coalesced row reads, validity folded) ----
    const float dx0 = pc_dest[(b * 3 + 0) * NNP + tid];
    const float dy0 = pc_dest[(b * 3 + 1) * NNP + tid];
    const float dz0 = pc_dest[(b * 3 + 2) * NNP + tid];
    const float dx1 = pc_dest[(b * 3 + 0) * NNP + tid + TPB];
    const float dy1 = pc_dest[(b * 3 + 1) * NNP + tid + TPB];
    const float dz1 = pc_dest[(b * 3 + 2) * NNP + tid + TPB];
    const bool v0 = (dx0 != 0.0f) && (dy0 != 0.0f) && (dz0 != 0.0f);
    const bool v1 = (dx1 != 0.0f) && (dy1 != 0.0f) && (dz1 != 0.0f);
    ds[tid]       = make_float4(dx0, dy0, dz0, v0 ? dx0*dx0 + dy0*dy0 + dz0*dz0 : INFINITY);
    ds[tid + TPB] = make_float4(dx1, dy1, dz1, v1 ? dx1*dx1 + dy1*dy1 + dz1*dz1 : INFINITY);

    // ---- prev partials (visible across kernel boundary) / init R,t ----
    if (it > 0) {
        sred[tid] = partials[(size_t)((it - 1) * BB + b) * (BPB * 32) + tid];
    } else {
        if (tid < 9) Rt[tid] = init_R[b * 9 + tid];
        if (tid < 3) Rt[9 + tid] = init_t[b * 3 + tid];
    }
    const float av = __syncthreads_or((int)(v0 || v1)) ? 1.0f : 0.0f;

    if (it > 0) {
        if (tid < NPART) {
            float s = 0.0f;
            #pragma unroll
            for (int c = 0; c < BPB; ++c) s += sred[c * 32 + tid];
            Sfin[tid] = s;
        }
        __syncthreads();
        // ---- redundant per-block Kabsch (identical arithmetic -> deterministic) ----
        if (tid == 0) {
            const float wsum = Sfin[0];
            if (wsum >= 0.5f) {
                const float safe = fmaxf(wsum, 1.0f);
                const float inv = 1.0f / safe;
                float mup[3], muq[3];
                #pragma unroll
                for (int i = 0; i < 3; ++i) { mup[i] = Sfin[1 + i] * inv; muq[i] = Sfin[4 + i] * inv; }
                float H[9];
                #pragma unroll
                for (int i = 0; i < 3; ++i)
                    #pragma unroll
                    for (int j = 0; j < 3; ++j)
                        H[i * 3 + j] = (Sfin[7 + i * 3 + j] * inv) - mup[i] * muq[j];
                const float detH = H[0] * (H[4]*H[8] - H[5]*H[7])
                                 - H[1] * (H[3]*H[8] - H[5]*H[6])
                                 + H[2] * (H[3]*H[7] - H[4]*H[6]);
                float R[9];
                if (detH > 1e-12f) {
                    // Kabsch R (det>0) == polar factor of H^T; Newton iteration:
                    // X <- 0.5*(X + cof(X)/det(X)),  X^{-T} = cof(X)/det(X)
                    float X[9] = {H[0], H[3], H[6], H[1], H[4], H[7], H[2], H[5], H[8]};
                    const float mu = 1.0f / cbrtf(detH);   // det-normalize once
                    #pragma unroll
                    for (int k = 0; k < 9; ++k) X[k] *= mu;
                    #pragma unroll
                    for (int itn = 0; itn < 6; ++itn) {
                        const float C0 = X[4]*X[8] - X[5]*X[7];
                        const float C1 = X[5]*X[6] - X[3]*X[8];
                        const float C2 = X[3]*X[7] - X[4]*X[6];
                        const float C3 = X[2]*X[7] - X[1]*X[8];
                        const float C4 = X[0]*X[8] - X[2]*X[6];
                        const float C5 = X[1]*X[6] - X[0]*X[7];
                        const float C6 = X[1]*X[5] - X[2]*X[4];
                        const float C7 = X[2]*X[3] - X[0]*X[5];
                        const float C8 = X[0]*X[4] - X[1]*X[3];
                        const float det = X[0]*C0 + X[1]*C1 + X[2]*C2;
                        const float h = 0.5f / det;
                        X[0] = 0.5f*X[0] + h*C0; X[1] = 0.5f*X[1] + h*C1; X[2] = 0.5f*X[2] + h*C2;
                        X[3] = 0.5f*X[3] + h*C3; X[4] = 0.5f*X[4] + h*C4; X[5] = 0.5f*X[5] + h*C5;
                        X[6] = 0.5f*X[6] + h*C6; X[7] = 0.5f*X[7] + h*C7; X[8] = 0.5f*X[8] + h*C8;
                    }
                    #pragma unroll
                    for (int k = 0; k < 9; ++k) R[k] = X[k];
                } else {
                    float H33[3][3], R33[3][3];
                    #pragma unroll
                    for (int i = 0; i < 3; ++i)
                        #pragma unroll
                        for (int j = 0; j < 3; ++j) H33[i][j] = H[i * 3 + j];
                    kabsch3f(H33, R33);
                    #pragma unroll
                    for (int i = 0; i < 3; ++i)
                        #pragma unroll
                        for (int j = 0; j < 3; ++j) R[i * 3 + j] = R33[i][j];
                }
                #pragma unroll
                for (int k = 0; k < 9; ++k) Rt[k] = R[k];
                #pragma unroll
                for (int i = 0; i < 3; ++i)
                    Rt[9 + i] = muq[i] - (R[i*3+0] * mup[0] + R[i*3+1] * mup[1] + R[i*3+2] * mup[2]);
            } else {
                // keep previous R/t (persisted by the previous launch)
                #pragma unroll
                for (int k = 0; k < 12; ++k) Rt[k] = rtstore[b * 16 + k];
            }
        }
        __syncthreads();
    }

    // ---- persist this launch's R/t; final-iteration R/t output ----
    if (cblk == 0 && tid < 12) {
        rtstore[b * 16 + tid] = Rt[tid];
        if (it == NITER) {
            if (tid < 9) out[b * 9 + tid] = Rt[tid];
            else out[72 + b * 3 + (tid - 9)] = Rt[tid];
        }
    }

    // ---- this pair's 8 source points (batch-0 source per reference) ----
    const int m0 = cblk * (WPB / 2 * TM) + pairid * TM;
    float sx[TM], sy[TM], sz[TM];
    #pragma unroll
    for (int t = 0; t < TM; ++t) {
        sx[t] = pc_src[0 * MM + m0 + t];
        sy[t] = pc_src[1 * MM + m0 + t];
        sz[t] = pc_src[2 * MM + m0 + t];
    }
    const int base = half * HALF;

    // ---- transform (argmin key drops per-m constant |p|^2) ----
    float nx[TM], ny[TM], nz[TM];
    #pragma unroll
    for (int t = 0; t < TM; ++t) {
        const float px = fmaf(Rt[0], sx[t], fmaf(Rt[1], sy[t], fmaf(Rt[2], sz[t], Rt[9])));
        const float py = fmaf(Rt[3], sx[t], fmaf(Rt[4], sy[t], fmaf(Rt[5], sz[t], Rt[10])));
        const float pz = fmaf(Rt[6], sx[t], fmaf(Rt[7], sy[t], fmaf(Rt[8], sz[t], Rt[11])));
        nx[t] = -2.0f * px; ny[t] = -2.0f * py; nz[t] = -2.0f * pz;
    }

    // ---- scan my half: 1 ds_read_b128 feeds 8 m-chains ----
    float best[TM]; int bidx[TM];
    #pragma unroll
    for (int t = 0; t < TM; ++t) { best[t] = INFINITY; bidx[t] = base + lane; }

    int j = base + lane;
    #pragma unroll 4
    for (int s = 0; s < STEPS; ++s, j += 64) {
        const float4 d = ds[j];
        #pragma unroll
        for (int t = 0; t < TM; ++t) {
            const float e = fmaf(nx[t], d.x, fmaf(ny[t], d.y, fmaf(nz[t], d.z, d.w)));
            if (e < best[t]) { best[t] = e; bidx[t] = j; }
        }
    }

    // ---- per-m cross-lane lex argmin (first-index tie-break) ----
    #pragma unroll
    for (int t = 0; t < TM; ++t) {
        float bv = best[t]; int bn = bidx[t];
        #pragma unroll
        for (int off = 32; off >= 1; off >>= 1) {
            const float ov = __shfl_xor(bv, off);
            const int on = __shfl_xor(bn, off);
            if (ov < bv || (ov == bv && on < bn)) { bv = ov; bn = on; }
        }
        best[t] = bv; bidx[t] = bn;
    }
    if (lane == 0) {
        #pragma unroll
        for (int t = 0; t < TM; ++t) { sminV[wid][t] = best[t]; sminI[wid][t] = bidx[t]; }
    }
    __syncthreads();

    // ---- even wave merges pair halves (tie -> even = lower index), moments ----
    if (!half) {
        float acc[NPART];
        #pragma unroll
        for (int k = 0; k < NPART; ++k) acc[k] = 0.0f;
        #pragma unroll
        for (int t = 0; t < TM; ++t) {
            float bv = best[t]; int bn = bidx[t];
            const float vO = sminV[wid + 1][t];
            const int iO = sminI[wid + 1][t];
            if (vO < bv) { bv = vO; bn = iO; }
            const float4 q = ds[bn];     // wave-uniform broadcast
            const float px = -0.5f * nx[t], py = -0.5f * ny[t], pz = -0.5f * nz[t];
            const float ex = px - q.x, ey = py - q.y, ez = pz - q.z;
            const float d2m = ex * ex + ey * ey + ez * ez;
            const float w = (d2m < THR2) ? av : 0.0f;
            acc[0] += w;
            acc[1] += w * sx[t];  acc[2] += w * sy[t];  acc[3] += w * sz[t];
            acc[4] += w * q.x;    acc[5] += w * q.y;    acc[6] += w * q.z;
            acc[7]  += w * sx[t] * q.x; acc[8]  += w * sx[t] * q.y; acc[9]  += w * sx[t] * q.z;
            acc[10] += w * sy[t] * q.x; acc[11] += w * sy[t] * q.y; acc[12] += w * sy[t] * q.z;
            acc[13] += w * sz[t] * q.x; acc[14] += w * sz[t] * q.y; acc[15] += w * sz[t] * q.z;
            acc[16] += w * d2m;
        }
        if (lane == 0) {
            #pragma unroll
            for (int k = 0; k < NPART; ++k) smom[pairid][k] = acc[k];
        }
    }
    __syncthreads();

    // ---- block moments -> this block's partial row ----
    if (tid < NPART) {
        float s = 0.0f;
        #pragma unroll
        for (int p = 0; p < WPB / 2; ++p) s += smom[p][tid];
        partials[(size_t)((it * BB + b) * BPB + cblk) * 32 + tid] = s;
    }
}

// ---------------- finalize: rmse from last partials ----------------
__global__ __launch_bounds__(64) void finalize_kernel(const float* __restrict__ partials,
                                                      float* __restrict__ out)
{
    const int b = blockIdx.x;
    const int lane = threadIdx.x;
    float w = 0.0f, wd = 0.0f;
    if (lane < BPB) {
        const float* row = partials + (size_t)((NITER * BB + b) * BPB + lane) * 32;
        w = row[0];
        wd = row[16];
    }
    #pragma unroll
    for (int off = 16; off >= 1; off >>= 1) {
        w += __shfl_xor(w, off);
        wd += __shfl_xor(wd, off);
    }
    if (lane == 0) {
        const float safe = fmaxf(w, 1.0f);
        const float rmse = sqrtf(wd / safe);
        out[96 + b] = (w > 0.0f) ? rmse : __builtin_nanf("");
    }
}

extern "C" void kernel_launch(void* const* d_in, const int* in_sizes, int n_in,
                              void* d_out, int out_size, void* d_ws, size_t ws_size,
                              hipStream_t stream) {
    const float* pc_src  = (const float*)d_in[0];
    const float* pc_dest = (const float*)d_in[1];
    const float* init_R  = (const float*)d_in[2];
    const float* init_t  = (const float*)d_in[3];
    float* out = (float*)d_out;
    float* ws = (float*)d_ws;

    // ws layout (floats)
    float* rtstore  = ws;                              // BB*16
    float* partials = ws + BB * 16;                    // (NITER+1)*BB*BPB*32

    for (int it = 0; it <= NITER; ++it) {
        corr_kernel<<<GRIDB, TPB, 0, stream>>>(it, pc_src, pc_dest, init_R, init_t,
                                               rtstore, partials, out);
    }
    finalize_kernel<<<BB, 64, 0, stream>>>(partials, out);
}